// Round 3
// baseline (44525.882 us; speedup 1.0000x reference)
//
#include <hip/hip_runtime.h>
#include <hip/hip_bf16.h>
#include <hip/hip_cooperative_groups.h>

namespace cg = cooperative_groups;

#define B 128
#define P 196
#define PH 98        // P/2 per half-block
#define PQ 49
#define ENC 512
#define DEC 512
#define ATT 256
#define EMB 256
#define V 5000
#define S 256
#define S1 257
#define NG 2048      // 4*DEC
#define KSC 8        // coop k-splits
#define KSL 16       // legacy k-splits

// ---------------- mean over P ----------------
__global__ __launch_bounds__(256) void k_mean(const float* __restrict__ feat,
                                              float* __restrict__ mean_f) {
    int idx = blockIdx.x * 256 + threadIdx.x;
    int b = idx >> 9, e = idx & 511;
    const float* fp = feat + (size_t)b * P * ENC + e;
    float s = 0.f;
    for (int p = 0; p < P; ++p) s += fp[(size_t)p * ENC];
    mean_f[idx] = s * (1.0f / (float)P);
}

// ---------------- h0 / c0 ----------------
__global__ __launch_bounds__(256) void k_init_hc(const float* __restrict__ mean_f,
        const float* __restrict__ ih_w, const float* __restrict__ ih_b,
        const float* __restrict__ ic_w, const float* __restrict__ ic_b,
        float* __restrict__ h, float* __restrict__ c) {
    int idx = blockIdx.x * 256 + threadIdx.x;
    int b = idx >> 9, d = idx & 511;
    const float* mf = mean_f + (size_t)b * ENC;
    float sh = ih_b[d], sc = ic_b[d];
    for (int e = 0; e < ENC; ++e) {
        float m = mf[e];
        sh = fmaf(m, ih_w[(size_t)e * DEC + d], sh);
        sc = fmaf(m, ic_w[(size_t)e * DEC + d], sc);
    }
    h[idx] = sh; c[idx] = sc;
}

// ---------------- Uf = features @ Ua_w + Ua_b ----------------
__global__ __launch_bounds__(256) void k_uf(const float* __restrict__ feat,
        const float* __restrict__ Ua_w, const float* __restrict__ Ua_b,
        float* __restrict__ Uf) {
    int row0 = blockIdx.x * 8;
    int a = threadIdx.x;
    __shared__ float fs[8][ENC];
    for (int i = threadIdx.x; i < 8 * ENC; i += 256) {
        int r = i >> 9, e = i & 511;
        fs[r][e] = feat[(size_t)(row0 + r) * ENC + e];
    }
    __syncthreads();
    float acc[8];
    float bia = Ua_b[a];
#pragma unroll
    for (int r = 0; r < 8; ++r) acc[r] = bia;
    for (int e = 0; e < ENC; ++e) {
        float w = Ua_w[(size_t)e * ATT + a];
#pragma unroll
        for (int r = 0; r < 8; ++r) acc[r] = fmaf(fs[r][e], w, acc[r]);
    }
#pragma unroll
    for (int r = 0; r < 8; ++r) Uf[(size_t)(row0 + r) * ATT + a] = acc[r];
}

// ---------------- Gemb = embeds[:, :S] @ W_ih[:EMB]  (bf16 out) ----------------
__global__ __launch_bounds__(256) void k_gemb(const float* __restrict__ emb,
        const int* __restrict__ captions, const float* __restrict__ W_ih,
        __hip_bfloat16* __restrict__ Gemb) {
    __shared__ float As[16][128];
    __shared__ float Bs[16][128];
    __shared__ int rowcap[128];
    int m0 = blockIdx.x * 128;
    int n0 = blockIdx.y * 128;
    int tid = threadIdx.x;
    if (tid < 128) {
        int m = m0 + tid;
        rowcap[tid] = captions[(size_t)(m & 127) * S1 + (m >> 7)];
    }
    __syncthreads();
    int tx = tid & 15, ty = tid >> 4;
    float acc[8][8];
#pragma unroll
    for (int i = 0; i < 8; ++i)
#pragma unroll
        for (int j = 0; j < 8; ++j) acc[i][j] = 0.f;
    int arow = tid >> 1, ak = (tid & 1) * 8;
    int bkk = tid >> 4, bn = (tid & 15) * 8;
    for (int k0 = 0; k0 < EMB; k0 += 16) {
        {
            const float* ap = emb + (size_t)rowcap[arow] * EMB + k0 + ak;
            float4 v0 = *(const float4*)ap;
            float4 v1 = *(const float4*)(ap + 4);
            As[ak + 0][arow] = v0.x; As[ak + 1][arow] = v0.y;
            As[ak + 2][arow] = v0.z; As[ak + 3][arow] = v0.w;
            As[ak + 4][arow] = v1.x; As[ak + 5][arow] = v1.y;
            As[ak + 6][arow] = v1.z; As[ak + 7][arow] = v1.w;
        }
        {
            const float* bp = W_ih + (size_t)(k0 + bkk) * NG + n0 + bn;
            *(float4*)&Bs[bkk][bn] = *(const float4*)bp;
            *(float4*)&Bs[bkk][bn + 4] = *(const float4*)(bp + 4);
        }
        __syncthreads();
#pragma unroll
        for (int kk = 0; kk < 16; ++kk) {
            float4 a0 = *(const float4*)&As[kk][ty * 8];
            float4 a1 = *(const float4*)&As[kk][ty * 8 + 4];
            float4 b0 = *(const float4*)&Bs[kk][tx * 8];
            float4 b1 = *(const float4*)&Bs[kk][tx * 8 + 4];
            float av[8] = {a0.x, a0.y, a0.z, a0.w, a1.x, a1.y, a1.z, a1.w};
            float bv[8] = {b0.x, b0.y, b0.z, b0.w, b1.x, b1.y, b1.z, b1.w};
#pragma unroll
            for (int i = 0; i < 8; ++i)
#pragma unroll
                for (int j = 0; j < 8; ++j)
                    acc[i][j] = fmaf(av[i], bv[j], acc[i][j]);
        }
        __syncthreads();
    }
#pragma unroll
    for (int i = 0; i < 8; ++i) {
        __hip_bfloat16* gp = Gemb + (size_t)(m0 + ty * 8 + i) * NG + n0 + tx * 8;
#pragma unroll
        for (int j = 0; j < 8; ++j) gp[j] = __float2bfloat16(acc[i][j]);
    }
}

// ================= persistent cooperative recurrence kernel =================
struct CoopParams {
    const float* feat; const int* captions; const float* emb;
    const float* Wa_w; const float* Wa_b; const float* va_w; const float* va_b;
    const float* W_ih; const float* b_ih; const float* W_hh; const float* b_hh;
    const float* Uf;
    const __hip_bfloat16* Gemb;
    float* h; float* c0; float* c1;
    float* Hall; float* partials; float* ctxp; float* mlp;
    int use_gemb;
};

__global__ __launch_bounds__(1024, 4) void k_loop(CoopParams pr) {
    cg::grid_group grid = cg::this_grid();
    const int g = blockIdx.x;
    const int tid = threadIdx.x;
    const int b = g >> 1, half = g & 1;

    __shared__ float hs[DEC];
    __shared__ float wah4[4][ATT];
    __shared__ float wah[ATT];
    __shared__ float sc[PH];
    __shared__ float red[8];
    __shared__ float cpart[2][ENC];
    __shared__ float As[16][128];
    __shared__ float Bs[16][64];
    __shared__ float sw0[B], sw1[B];
    __shared__ int scap[B];

    for (int t = 0; t <= S; ++t) {
        // ---- cell: consume partials(t-1) -> h_t, c_t ----
        if (t > 0) {
            if (tid < DEC) {
                int d = tid;
                size_t idx = (size_t)b * DEC + d;
                float s0 = pr.b_ih[d]           + pr.b_hh[d];
                float s1 = pr.b_ih[d + DEC]     + pr.b_hh[d + DEC];
                float s2 = pr.b_ih[d + 2 * DEC] + pr.b_hh[d + 2 * DEC];
                float s3 = pr.b_ih[d + 3 * DEC] + pr.b_hh[d + 3 * DEC];
                for (int ks = 0; ks < KSC; ++ks) {
                    const float* pp = pr.partials + ((size_t)ks * B + b) * NG + d;
                    s0 += pp[0]; s1 += pp[DEC]; s2 += pp[2 * DEC]; s3 += pp[3 * DEC];
                }
                if (pr.use_gemb) {
                    const __hip_bfloat16* gp = pr.Gemb + ((size_t)(t - 1) * B + b) * NG + d;
                    s0 += __bfloat162float(gp[0]);
                    s1 += __bfloat162float(gp[DEC]);
                    s2 += __bfloat162float(gp[2 * DEC]);
                    s3 += __bfloat162float(gp[3 * DEC]);
                }
                const float* cr = (t & 1) ? pr.c0 : pr.c1;   // read c_{t-1}
                float*       cw = (t & 1) ? pr.c1 : pr.c0;   // write c_t
                float ii = 1.f / (1.f + __expf(-s0));
                float ff = 1.f / (1.f + __expf(-s1));
                float gg = tanhf(s2);
                float oo = 1.f / (1.f + __expf(-s3));
                float cn = ff * cr[idx] + ii * gg;
                float hn = oo * tanhf(cn);
                hs[d] = hn;
                if (half == 0) {
                    cw[idx] = cn;
                    pr.h[idx] = hn;
                    pr.Hall[((size_t)(t - 1) * B + b) * DEC + d] = hn;
                }
            }
        } else {
            if (tid < DEC) hs[tid] = pr.h[(size_t)b * DEC + tid];
        }
        __syncthreads();
        if (t == S) break;

        // ---- wah[a] = Wa_b[a] + sum_d hs[d]*Wa_w[d,a]  (d split over 4 groups) ----
        {
            int a = tid & 255, q = tid >> 8;
            float acc = 0.f;
            const float* wp = pr.Wa_w + (size_t)(q * 128) * ATT + a;
#pragma unroll 4
            for (int d = 0; d < 128; ++d)
                acc = fmaf(hs[q * 128 + d], wp[(size_t)d * ATT], acc);
            wah4[q][a] = acc;
        }
        __syncthreads();
        if (tid < ATT)
            wah[tid] = pr.Wa_b[tid] + wah4[0][tid] + wah4[1][tid] + wah4[2][tid] + wah4[3][tid];
        __syncthreads();

        // ---- scores for this half's 98 positions ----
        {
            int w = tid >> 6, lane = tid & 63;
            float4 wv = *(const float4*)&wah[lane * 4];
            float4 vv = *(const float4*)&pr.va_w[lane * 4];
            float vb = pr.va_b[0];
            for (int pl = w; pl < PH; pl += 16) {
                const float* ufp = pr.Uf + ((size_t)b * P + half * PH + pl) * ATT + lane * 4;
                float4 u = *(const float4*)ufp;
                float ssc = vv.x * tanhf(u.x + wv.x) + vv.y * tanhf(u.y + wv.y)
                          + vv.z * tanhf(u.z + wv.z) + vv.w * tanhf(u.w + wv.w);
#pragma unroll
                for (int off = 32; off; off >>= 1) ssc += __shfl_down(ssc, off);
                if (lane == 0) sc[pl] = ssc + vb;
            }
        }
        __syncthreads();

        // ---- local softmax over PH: m_h, l_h; sc <- unnormalized alpha ----
        {
            int lane = tid & 63;
            float v = (tid < PH) ? sc[tid] : -1e30f;
            if (tid < 128) {
                float m = v;
#pragma unroll
                for (int off = 32; off; off >>= 1) m = fmaxf(m, __shfl_down(m, off));
                if (lane == 0) red[tid >> 6] = m;
            }
            __syncthreads();
            float mh = fmaxf(red[0], red[1]);
            float e = (tid < PH) ? __expf(v - mh) : 0.f;
            if (tid < 128) {
                float l = e;
#pragma unroll
                for (int off = 32; off; off >>= 1) l += __shfl_down(l, off);
                if (lane == 0) red[2 + (tid >> 6)] = l;
            }
            __syncthreads();
            if (tid < PH) sc[tid] = e;
            if (tid == 0) {
                pr.mlp[((size_t)half * B + b) * 2 + 0] = mh;
                pr.mlp[((size_t)half * B + b) * 2 + 1] = red[2] + red[3];
            }
        }
        __syncthreads();

        // ---- partial context ----
        {
            int e = tid & 511, ph = tid >> 9;
            float acc = 0.f;
            const float* fb = pr.feat + ((size_t)b * P + half * PH + ph * PQ) * ENC + e;
            for (int i = 0; i < PQ; ++i)
                acc = fmaf(sc[ph * PQ + i], fb[(size_t)i * ENC], acc);
            cpart[ph][e] = acc;
        }
        __syncthreads();
        if (tid < ENC)
            pr.ctxp[((size_t)half * B + b) * ENC + tid] = cpart[0][tid] + cpart[1][tid];
        grid.sync();

        // ---- gates GEMM: 32 n-tiles x 8 k-splits, inline ctx combine ----
        {
            int n0 = (g & 31) * 64;
            int ks = g >> 5;
            int kch = pr.use_gemb ? 128 : 160;
            if (tid < B) {
                float m0 = pr.mlp[((size_t)0 * B + tid) * 2 + 0];
                float l0 = pr.mlp[((size_t)0 * B + tid) * 2 + 1];
                float m1 = pr.mlp[((size_t)1 * B + tid) * 2 + 0];
                float l1 = pr.mlp[((size_t)1 * B + tid) * 2 + 1];
                float M = fmaxf(m0, m1);
                float e0 = __expf(m0 - M), e1 = __expf(m1 - M);
                float inv = 1.f / (l0 * e0 + l1 * e1);
                sw0[tid] = e0 * inv; sw1[tid] = e1 * inv;
                if (!pr.use_gemb) scap[tid] = pr.captions[(size_t)tid * S1 + t];
            }
            __syncthreads();
            float acc[2][4] = {{0.f, 0.f, 0.f, 0.f}, {0.f, 0.f, 0.f, 0.f}};
            int arow = tid >> 3, ak = (tid & 7) * 2;
            int bkk = tid >> 6, bn = tid & 63;
            int tx = tid & 15, ty = tid >> 4;
            int kend = (ks + 1) * kch;
            for (int k0 = ks * kch; k0 < kend; k0 += 16) {
                {   // A tile (2 elems/thread)
                    int k = k0 + ak;
                    float a0, a1;
                    if (!pr.use_gemb && k < EMB) {
                        const float* ap = pr.emb + (size_t)scap[arow] * EMB + k;
                        a0 = ap[0]; a1 = ap[1];
                    } else {
                        int kc = pr.use_gemb ? k : (k - EMB);
                        if (kc < ENC) {
                            const float* p0a = pr.ctxp + ((size_t)0 * B + arow) * ENC + kc;
                            const float* p1a = pr.ctxp + ((size_t)1 * B + arow) * ENC + kc;
                            float w0 = sw0[arow], w1 = sw1[arow];
                            a0 = p0a[0] * w0 + p1a[0] * w1;
                            a1 = p0a[1] * w0 + p1a[1] * w1;
                        } else {
                            const float* ap = pr.h + (size_t)arow * DEC + (kc - ENC);
                            a0 = ap[0]; a1 = ap[1];
                        }
                    }
                    As[ak][arow] = a0;
                    As[ak + 1][arow] = a1;
                }
                {   // B tile (1 elem/thread)
                    int k = k0 + bkk;
                    const float* bp;
                    if (pr.use_gemb)
                        bp = (k < ENC) ? pr.W_ih + (size_t)(k + EMB) * NG + n0 + bn
                                       : pr.W_hh + (size_t)(k - ENC) * NG + n0 + bn;
                    else
                        bp = (k < EMB + ENC) ? pr.W_ih + (size_t)k * NG + n0 + bn
                                             : pr.W_hh + (size_t)(k - EMB - ENC) * NG + n0 + bn;
                    Bs[bkk][bn] = *bp;
                }
                __syncthreads();
#pragma unroll
                for (int kk = 0; kk < 16; ++kk) {
                    float a0 = As[kk][ty * 2], a1 = As[kk][ty * 2 + 1];
                    float4 b4 = *(const float4*)&Bs[kk][tx * 4];
                    acc[0][0] = fmaf(a0, b4.x, acc[0][0]);
                    acc[0][1] = fmaf(a0, b4.y, acc[0][1]);
                    acc[0][2] = fmaf(a0, b4.z, acc[0][2]);
                    acc[0][3] = fmaf(a0, b4.w, acc[0][3]);
                    acc[1][0] = fmaf(a1, b4.x, acc[1][0]);
                    acc[1][1] = fmaf(a1, b4.y, acc[1][1]);
                    acc[1][2] = fmaf(a1, b4.z, acc[1][2]);
                    acc[1][3] = fmaf(a1, b4.w, acc[1][3]);
                }
                __syncthreads();
            }
            float* pp = pr.partials + ((size_t)ks * B + ty * 2) * NG + n0 + tx * 4;
            *(float4*)pp = make_float4(acc[0][0], acc[0][1], acc[0][2], acc[0][3]);
            *(float4*)(pp + NG) = make_float4(acc[1][0], acc[1][1], acc[1][2], acc[1][3]);
        }
        grid.sync();
    }
}

// ================= legacy fallback kernels (round-2 path) =================
__global__ __launch_bounds__(256) void k_attn_cell(
        const float* __restrict__ partials, const __hip_bfloat16* __restrict__ Gemb,
        const float* __restrict__ b_ih, const float* __restrict__ b_hh,
        float* __restrict__ h, float* __restrict__ c, float* __restrict__ Hall,
        const float* __restrict__ Uf, const float* __restrict__ feat,
        const float* __restrict__ Wa_w, const float* __restrict__ Wa_b,
        const float* __restrict__ va_w, const float* __restrict__ va_b,
        float* __restrict__ ctx, int t, int use_gemb, int use_hall) {
    int b = blockIdx.x;
    int tid = threadIdx.x;
    __shared__ float hs[DEC];
    __shared__ float wah[ATT];
    __shared__ float sc[P];
    __shared__ float red[8];

    if (t > 0) {
        float s[2][4];
#pragma unroll
        for (int j = 0; j < 2; ++j)
#pragma unroll
            for (int q = 0; q < 4; ++q) {
                int n = q * DEC + j * 256 + tid;
                s[j][q] = b_ih[n] + b_hh[n];
            }
        for (int ks = 0; ks < KSL; ++ks) {
            const float* pp = partials + ((size_t)ks * B + b) * NG;
#pragma unroll
            for (int j = 0; j < 2; ++j)
#pragma unroll
                for (int q = 0; q < 4; ++q)
                    s[j][q] += pp[q * DEC + j * 256 + tid];
        }
        if (use_gemb) {
            const __hip_bfloat16* gp = Gemb + ((size_t)(t - 1) * B + b) * NG;
#pragma unroll
            for (int j = 0; j < 2; ++j)
#pragma unroll
                for (int q = 0; q < 4; ++q)
                    s[j][q] += __bfloat162float(gp[q * DEC + j * 256 + tid]);
        }
#pragma unroll
        for (int j = 0; j < 2; ++j) {
            int d = j * 256 + tid;
            float ii = 1.f / (1.f + __expf(-s[j][0]));
            float ff = 1.f / (1.f + __expf(-s[j][1]));
            float gg = tanhf(s[j][2]);
            float oo = 1.f / (1.f + __expf(-s[j][3]));
            size_t idx = (size_t)b * DEC + d;
            float cn = ff * c[idx] + ii * gg;
            float hn = oo * tanhf(cn);
            c[idx] = cn; h[idx] = hn; hs[d] = hn;
            if (use_hall) Hall[((size_t)(t - 1) * B + b) * DEC + d] = hn;
        }
    } else {
        for (int d = tid; d < DEC; d += 256) hs[d] = h[(size_t)b * DEC + d];
    }
    if (t == S) return;
    __syncthreads();

    {
        int a = tid;
        float ssum = Wa_b[a];
#pragma unroll 4
        for (int d = 0; d < DEC; ++d) ssum = fmaf(hs[d], Wa_w[(size_t)d * ATT + a], ssum);
        wah[a] = ssum;
    }
    __syncthreads();
    int wave = tid >> 6, lane = tid & 63;
    const float vb = va_b[0];
    for (int p = wave; p < P; p += 4) {
        const float* ufp = Uf + ((size_t)b * P + p) * ATT + lane * 4;
        float4 u = *(const float4*)ufp;
        float4 w4 = *(const float4*)&wah[lane * 4];
        float4 v4 = *(const float4*)&va_w[lane * 4];
        float ssc = v4.x * tanhf(u.x + w4.x) + v4.y * tanhf(u.y + w4.y)
                  + v4.z * tanhf(u.z + w4.z) + v4.w * tanhf(u.w + w4.w);
#pragma unroll
        for (int off = 32; off; off >>= 1) ssc += __shfl_down(ssc, off);
        if (lane == 0) sc[p] = ssc + vb;
    }
    __syncthreads();
    float v = (tid < P) ? sc[tid] : -1e30f;
    float m = v;
#pragma unroll
    for (int off = 32; off; off >>= 1) m = fmaxf(m, __shfl_down(m, off));
    if (lane == 0) red[wave] = m;
    __syncthreads();
    if (tid == 0) red[4] = fmaxf(fmaxf(red[0], red[1]), fmaxf(red[2], red[3]));
    __syncthreads();
    float mm = red[4];
    float e = (tid < P) ? __expf(v - mm) : 0.f;
    float ssum = e;
#pragma unroll
    for (int off = 32; off; off >>= 1) ssum += __shfl_down(ssum, off);
    if (lane == 0) red[wave] = ssum;
    __syncthreads();
    if (tid == 0) red[5] = 1.0f / (red[0] + red[1] + red[2] + red[3]);
    __syncthreads();
    float inv = red[5];
    if (tid < P) sc[tid] = e * inv;
    __syncthreads();
    float acc0 = 0.f, acc1 = 0.f;
    const float* fb = feat + (size_t)b * P * ENC;
    for (int p = 0; p < P; ++p) {
        float al = sc[p];
        acc0 = fmaf(al, fb[(size_t)p * ENC + tid], acc0);
        acc1 = fmaf(al, fb[(size_t)p * ENC + tid + 256], acc1);
    }
    ctx[(size_t)b * ENC + tid] = acc0;
    ctx[(size_t)b * ENC + tid + 256] = acc1;
}

__global__ __launch_bounds__(256) void k_gates(const float* __restrict__ emb,
        const int* __restrict__ captions, int t,
        const float* __restrict__ ctx, const float* __restrict__ h,
        const float* __restrict__ W_ih, const float* __restrict__ W_hh,
        float* __restrict__ partials, int kch, int use_gemb) {
    __shared__ float As[16][128];
    __shared__ float Bs[16][64];
    __shared__ int scap[B];
    int n0 = blockIdx.x * 64;
    int ks = blockIdx.y;
    int tid = threadIdx.x;
    if (!use_gemb && tid < B) scap[tid] = captions[(size_t)tid * S1 + t];
    __syncthreads();
    int tx = tid & 15, ty = tid >> 4;
    float acc[8][4];
#pragma unroll
    for (int i = 0; i < 8; ++i)
#pragma unroll
        for (int j = 0; j < 4; ++j) acc[i][j] = 0.f;
    int arow = tid >> 1, ak = (tid & 1) * 8;
    int bkk = tid >> 4, bn = (tid & 15) * 4;
    for (int k0 = ks * kch; k0 < ks * kch + kch; k0 += 16) {
        const float* ap;
        if (use_gemb) {
            ap = (k0 < ENC) ? ctx + (size_t)arow * ENC + k0
                            : h + (size_t)arow * DEC + (k0 - ENC);
        } else {
            if (k0 < EMB)            ap = emb + (size_t)scap[arow] * EMB + k0;
            else if (k0 < EMB + ENC) ap = ctx + (size_t)arow * ENC + (k0 - EMB);
            else                     ap = h + (size_t)arow * DEC + (k0 - EMB - ENC);
        }
        float4 v0 = *(const float4*)(ap + ak);
        float4 v1 = *(const float4*)(ap + ak + 4);
        As[ak + 0][arow] = v0.x; As[ak + 1][arow] = v0.y;
        As[ak + 2][arow] = v0.z; As[ak + 3][arow] = v0.w;
        As[ak + 4][arow] = v1.x; As[ak + 5][arow] = v1.y;
        As[ak + 6][arow] = v1.z; As[ak + 7][arow] = v1.w;
        int k = k0 + bkk;
        const float* bp;
        if (use_gemb) {
            bp = (k < ENC) ? W_ih + (size_t)(k + EMB) * NG + n0 + bn
                           : W_hh + (size_t)(k - ENC) * NG + n0 + bn;
        } else {
            bp = (k < EMB + ENC) ? W_ih + (size_t)k * NG + n0 + bn
                                 : W_hh + (size_t)(k - EMB - ENC) * NG + n0 + bn;
        }
        *(float4*)&Bs[bkk][bn] = *(const float4*)bp;
        __syncthreads();
#pragma unroll
        for (int kk = 0; kk < 16; ++kk) {
            float4 a0 = *(const float4*)&As[kk][ty * 8];
            float4 a1 = *(const float4*)&As[kk][ty * 8 + 4];
            float4 b0 = *(const float4*)&Bs[kk][tx * 4];
            float av[8] = {a0.x, a0.y, a0.z, a0.w, a1.x, a1.y, a1.z, a1.w};
            float bv[4] = {b0.x, b0.y, b0.z, b0.w};
#pragma unroll
            for (int i = 0; i < 8; ++i)
#pragma unroll
                for (int j = 0; j < 4; ++j)
                    acc[i][j] = fmaf(av[i], bv[j], acc[i][j]);
        }
        __syncthreads();
    }
#pragma unroll
    for (int i = 0; i < 8; ++i) {
        int mrow = ty * 8 + i;
        float* pp = partials + ((size_t)ks * B + mrow) * NG + n0 + tx * 4;
        *(float4*)pp = make_float4(acc[i][0], acc[i][1], acc[i][2], acc[i][3]);
    }
}

// ---------------- output projection GEMM ----------------
__global__ __launch_bounds__(256) void k_fcn(const float* __restrict__ A,
        const float* __restrict__ Bw, const float* __restrict__ bias,
        float* __restrict__ out, int t_fix) {
    __shared__ float As[16][128];
    __shared__ float Bs[16][128];
    int m0 = blockIdx.x * 128;
    int n0 = blockIdx.y * 128;
    int tid = threadIdx.x;
    int tx = tid & 15, ty = tid >> 4;
    float acc[8][8];
#pragma unroll
    for (int i = 0; i < 8; ++i)
#pragma unroll
        for (int j = 0; j < 8; ++j) acc[i][j] = 0.f;
    int arow = tid >> 1, ak = (tid & 1) * 8;
    int bkk = tid >> 4, bn = (tid & 15) * 8;
    const float4 z4 = make_float4(0.f, 0.f, 0.f, 0.f);
    for (int k0 = 0; k0 < DEC; k0 += 16) {
        {
            const float* ap = A + (size_t)(m0 + arow) * DEC + k0 + ak;
            float4 v0 = *(const float4*)ap;
            float4 v1 = *(const float4*)(ap + 4);
            As[ak + 0][arow] = v0.x; As[ak + 1][arow] = v0.y;
            As[ak + 2][arow] = v0.z; As[ak + 3][arow] = v0.w;
            As[ak + 4][arow] = v1.x; As[ak + 5][arow] = v1.y;
            As[ak + 6][arow] = v1.z; As[ak + 7][arow] = v1.w;
        }
        {
            int n4 = n0 + bn;
            const float* bp = Bw + (size_t)(k0 + bkk) * V + n4;
            float4 v0 = (n4 < V) ? *(const float4*)bp : z4;
            float4 v1 = (n4 + 4 < V) ? *(const float4*)(bp + 4) : z4;
            *(float4*)&Bs[bkk][bn] = v0;
            *(float4*)&Bs[bkk][bn + 4] = v1;
        }
        __syncthreads();
#pragma unroll
        for (int kk = 0; kk < 16; ++kk) {
            float4 a0 = *(const float4*)&As[kk][ty * 8];
            float4 a1 = *(const float4*)&As[kk][ty * 8 + 4];
            float4 b0 = *(const float4*)&Bs[kk][tx * 8];
            float4 b1 = *(const float4*)&Bs[kk][tx * 8 + 4];
            float av[8] = {a0.x, a0.y, a0.z, a0.w, a1.x, a1.y, a1.z, a1.w};
            float bv[8] = {b0.x, b0.y, b0.z, b0.w, b1.x, b1.y, b1.z, b1.w};
#pragma unroll
            for (int i = 0; i < 8; ++i)
#pragma unroll
                for (int j = 0; j < 8; ++j)
                    acc[i][j] = fmaf(av[i], bv[j], acc[i][j]);
        }
        __syncthreads();
    }
#pragma unroll
    for (int i = 0; i < 8; ++i) {
        int mrow = m0 + ty * 8 + i;
        int bb, tt;
        if (t_fix >= 0) { bb = mrow; tt = t_fix; }
        else            { tt = mrow >> 7; bb = mrow & 127; }
        float* op = out + ((size_t)bb * S + tt) * V + n0 + tx * 8;
#pragma unroll
        for (int j = 0; j < 8; ++j) {
            int n = n0 + tx * 8 + j;
            if (n < V) op[j] = acc[i][j] + bias[n];
        }
    }
}

extern "C" void kernel_launch(void* const* d_in, const int* in_sizes, int n_in,
                              void* d_out, int out_size, void* d_ws, size_t ws_size,
                              hipStream_t stream) {
    const float* features = (const float*)d_in[0];
    const int*   captions = (const int*)d_in[1];
    const float* emb      = (const float*)d_in[2];
    const float* Ua_w     = (const float*)d_in[3];
    const float* Ua_b     = (const float*)d_in[4];
    const float* Wa_w     = (const float*)d_in[5];
    const float* Wa_b     = (const float*)d_in[6];
    const float* va_w     = (const float*)d_in[7];
    const float* va_b     = (const float*)d_in[8];
    const float* ih_w     = (const float*)d_in[9];
    const float* ih_b     = (const float*)d_in[10];
    const float* ic_w     = (const float*)d_in[11];
    const float* ic_b     = (const float*)d_in[12];
    const float* W_ih     = (const float*)d_in[13];
    const float* b_ih     = (const float*)d_in[14];
    const float* W_hh     = (const float*)d_in[15];
    const float* b_hh     = (const float*)d_in[16];
    const float* fcn_w    = (const float*)d_in[17];
    const float* fcn_b    = (const float*)d_in[18];
    float* out = (float*)d_out;
    char* wsb  = (char*)d_ws;

    size_t off = 0;
    float* Uf       = (float*)(wsb + off); off += (size_t)B * P * ATT * 4;   // 25.7MB
    float* Hall     = (float*)(wsb + off); off += (size_t)S * B * DEC * 4;   // 67MB
    float* hbuf     = (float*)(wsb + off); off += (size_t)B * DEC * 4;
    float* cbuf0    = (float*)(wsb + off); off += (size_t)B * DEC * 4;
    float* cbuf1    = (float*)(wsb + off); off += (size_t)B * DEC * 4;
    float* partials = (float*)(wsb + off); off += (size_t)KSL * B * NG * 4;  // 16.8MB
    float* ctxp     = (float*)(wsb + off); off += (size_t)2 * B * ENC * 4;
    float* mlp      = (float*)(wsb + off); off += 4096;
    float* meanf    = (float*)(wsb + off); off += (size_t)B * ENC * 4;
    float* ctxbuf   = (float*)(wsb + off); off += (size_t)B * ENC * 4;
    size_t need_base = off;
    __hip_bfloat16* Gemb = (__hip_bfloat16*)(wsb + off);
    off += (size_t)S * B * NG * 2;                                           // 134MB
    size_t need_gemb = off;

    int have_base = ws_size >= need_base;
    int use_gemb  = ws_size >= need_gemb;

    k_mean<<<256, 256, 0, stream>>>(features, meanf);
    k_init_hc<<<256, 256, 0, stream>>>(meanf, ih_w, ih_b, ic_w, ic_b, hbuf, cbuf0);
    k_uf<<<3136, 256, 0, stream>>>(features, Ua_w, Ua_b, Uf);
    if (use_gemb)
        k_gemb<<<dim3(256, 16), 256, 0, stream>>>(emb, captions, W_ih, Gemb);

    bool coop_done = false;
    if (have_base) {
        CoopParams pr;
        pr.feat = features; pr.captions = captions; pr.emb = emb;
        pr.Wa_w = Wa_w; pr.Wa_b = Wa_b; pr.va_w = va_w; pr.va_b = va_b;
        pr.W_ih = W_ih; pr.b_ih = b_ih; pr.W_hh = W_hh; pr.b_hh = b_hh;
        pr.Uf = Uf; pr.Gemb = Gemb;
        pr.h = hbuf; pr.c0 = cbuf0; pr.c1 = cbuf1;
        pr.Hall = Hall; pr.partials = partials; pr.ctxp = ctxp; pr.mlp = mlp;
        pr.use_gemb = use_gemb;
        void* args[] = { &pr };
        hipError_t err = hipLaunchCooperativeKernel((const void*)k_loop,
                dim3(256), dim3(1024), args, 0, stream);
        if (err == hipSuccess) {
            coop_done = true;
            k_fcn<<<dim3(256, 40), 256, 0, stream>>>(Hall, fcn_w, fcn_b, out, -1);
        }
    }

    if (!coop_done) {
        // legacy per-step path (round-2 structure)
        int kch = use_gemb ? 64 : 80;
        for (int t = 0; t <= S; ++t) {
            k_attn_cell<<<128, 256, 0, stream>>>(partials, Gemb, b_ih, b_hh,
                    hbuf, cbuf0, Hall, Uf, features, Wa_w, Wa_b, va_w, va_b,
                    ctxbuf, t, use_gemb, have_base);
            if (t < S)
                k_gates<<<dim3(32, KSL), 256, 0, stream>>>(emb, captions, t, ctxbuf, hbuf,
                        W_ih, W_hh, partials, kch, use_gemb);
            if (!have_base && t > 0)
                k_fcn<<<dim3(1, 40), 256, 0, stream>>>(hbuf, fcn_w, fcn_b, out, t - 1);
        }
        if (have_base)
            k_fcn<<<dim3(256, 40), 256, 0, stream>>>(Hall, fcn_w, fcn_b, out, -1);
    }
}

// Round 4
// 16789.055 us; speedup vs baseline: 2.6521x; 2.6521x over previous
//
#include <hip/hip_runtime.h>
#include <hip/hip_bf16.h>

#define B 128
#define P 196
#define PH 98        // P/2 per half-block
#define ENC 512
#define DEC 512
#define ATT 256
#define EMB 256
#define V 5000
#define S 256
#define S1 257
#define NG 2048      // 4*DEC
#define KS 8         // k-splits for gates GEMM

// ---------------- mean over P ----------------
__global__ __launch_bounds__(256) void k_mean(const float* __restrict__ feat,
                                              float* __restrict__ mean_f) {
    int idx = blockIdx.x * 256 + threadIdx.x;
    int b = idx >> 9, e = idx & 511;
    const float* fp = feat + (size_t)b * P * ENC + e;
    float s = 0.f;
    for (int p = 0; p < P; ++p) s += fp[(size_t)p * ENC];
    mean_f[idx] = s * (1.0f / (float)P);
}

// ---------------- h0 / c0 ----------------
__global__ __launch_bounds__(256) void k_init_hc(const float* __restrict__ mean_f,
        const float* __restrict__ ih_w, const float* __restrict__ ih_b,
        const float* __restrict__ ic_w, const float* __restrict__ ic_b,
        float* __restrict__ h, float* __restrict__ c) {
    int idx = blockIdx.x * 256 + threadIdx.x;
    int b = idx >> 9, d = idx & 511;
    const float* mf = mean_f + (size_t)b * ENC;
    float sh = ih_b[d], sc = ic_b[d];
    for (int e = 0; e < ENC; ++e) {
        float m = mf[e];
        sh = fmaf(m, ih_w[(size_t)e * DEC + d], sh);
        sc = fmaf(m, ic_w[(size_t)e * DEC + d], sc);
    }
    h[idx] = sh; c[idx] = sc;
}

// ---------------- Uf = features @ Ua_w + Ua_b ----------------
__global__ __launch_bounds__(256) void k_uf(const float* __restrict__ feat,
        const float* __restrict__ Ua_w, const float* __restrict__ Ua_b,
        float* __restrict__ Uf) {
    int row0 = blockIdx.x * 8;
    int a = threadIdx.x;
    __shared__ float fs[8][ENC];
    for (int i = threadIdx.x; i < 8 * ENC; i += 256) {
        int r = i >> 9, e = i & 511;
        fs[r][e] = feat[(size_t)(row0 + r) * ENC + e];
    }
    __syncthreads();
    float acc[8];
    float bia = Ua_b[a];
#pragma unroll
    for (int r = 0; r < 8; ++r) acc[r] = bia;
    for (int e = 0; e < ENC; ++e) {
        float w = Ua_w[(size_t)e * ATT + a];
#pragma unroll
        for (int r = 0; r < 8; ++r) acc[r] = fmaf(fs[r][e], w, acc[r]);
    }
#pragma unroll
    for (int r = 0; r < 8; ++r) Uf[(size_t)(row0 + r) * ATT + a] = acc[r];
}

// ---------------- Gemb = embeds[:, :S] @ W_ih[:EMB]  (bf16 out) ----------------
__global__ __launch_bounds__(256) void k_gemb(const float* __restrict__ emb,
        const int* __restrict__ captions, const float* __restrict__ W_ih,
        __hip_bfloat16* __restrict__ Gemb) {
    __shared__ float As[16][128];
    __shared__ float Bs[16][128];
    __shared__ int rowcap[128];
    int m0 = blockIdx.x * 128;
    int n0 = blockIdx.y * 128;
    int tid = threadIdx.x;
    if (tid < 128) {
        int m = m0 + tid;
        rowcap[tid] = captions[(size_t)(m & 127) * S1 + (m >> 7)];
    }
    __syncthreads();
    int tx = tid & 15, ty = tid >> 4;
    float acc[8][8];
#pragma unroll
    for (int i = 0; i < 8; ++i)
#pragma unroll
        for (int j = 0; j < 8; ++j) acc[i][j] = 0.f;
    int arow = tid >> 1, ak = (tid & 1) * 8;
    int bkk = tid >> 4, bn = (tid & 15) * 8;
    for (int k0 = 0; k0 < EMB; k0 += 16) {
        {
            const float* ap = emb + (size_t)rowcap[arow] * EMB + k0 + ak;
            float4 v0 = *(const float4*)ap;
            float4 v1 = *(const float4*)(ap + 4);
            As[ak + 0][arow] = v0.x; As[ak + 1][arow] = v0.y;
            As[ak + 2][arow] = v0.z; As[ak + 3][arow] = v0.w;
            As[ak + 4][arow] = v1.x; As[ak + 5][arow] = v1.y;
            As[ak + 6][arow] = v1.z; As[ak + 7][arow] = v1.w;
        }
        {
            const float* bp = W_ih + (size_t)(k0 + bkk) * NG + n0 + bn;
            *(float4*)&Bs[bkk][bn] = *(const float4*)bp;
            *(float4*)&Bs[bkk][bn + 4] = *(const float4*)(bp + 4);
        }
        __syncthreads();
#pragma unroll
        for (int kk = 0; kk < 16; ++kk) {
            float4 a0 = *(const float4*)&As[kk][ty * 8];
            float4 a1 = *(const float4*)&As[kk][ty * 8 + 4];
            float4 b0 = *(const float4*)&Bs[kk][tx * 8];
            float4 b1 = *(const float4*)&Bs[kk][tx * 8 + 4];
            float av[8] = {a0.x, a0.y, a0.z, a0.w, a1.x, a1.y, a1.z, a1.w};
            float bv[8] = {b0.x, b0.y, b0.z, b0.w, b1.x, b1.y, b1.z, b1.w};
#pragma unroll
            for (int i = 0; i < 8; ++i)
#pragma unroll
                for (int j = 0; j < 8; ++j)
                    acc[i][j] = fmaf(av[i], bv[j], acc[i][j]);
        }
        __syncthreads();
    }
#pragma unroll
    for (int i = 0; i < 8; ++i) {
        __hip_bfloat16* gp = Gemb + (size_t)(m0 + ty * 8 + i) * NG + n0 + tx * 8;
#pragma unroll
        for (int j = 0; j < 8; ++j) gp[j] = __float2bfloat16(acc[i][j]);
    }
}

// ---------------- cell (reduce partials) + m-tiled wah GEMV ----------------
// 32 blocks x 1024 threads; block owns 4 batch rows.
// t==0: wah only (h from hbuf). t==S: cell only.
__global__ __launch_bounds__(1024) void k_cellwah(
        const float* __restrict__ partials, const __hip_bfloat16* __restrict__ Gemb,
        const float* __restrict__ b_ih, const float* __restrict__ b_hh,
        float* __restrict__ h, float* __restrict__ c, float* __restrict__ Hall,
        const float* __restrict__ Wa_w, const float* __restrict__ Wa_b,
        float* __restrict__ wahbuf, int t, int use_gemb, int use_hall) {
    int bb0 = blockIdx.x * 4;
    int tid = threadIdx.x;
    __shared__ float hs[4][DEC];
    __shared__ float wahp[4][4][ATT];

    if (t > 0) {
#pragma unroll
        for (int i = 0; i < 2; ++i) {
            int idx = i * 1024 + tid;           // 0..2047 over 4b x 512d
            int bl = idx >> 9, d = idx & 511;
            int b = bb0 + bl;
            float s0 = b_ih[d]           + b_hh[d];
            float s1 = b_ih[d + DEC]     + b_hh[d + DEC];
            float s2 = b_ih[d + 2 * DEC] + b_hh[d + 2 * DEC];
            float s3 = b_ih[d + 3 * DEC] + b_hh[d + 3 * DEC];
            for (int ks = 0; ks < KS; ++ks) {
                const float* pp = partials + ((size_t)ks * B + b) * NG + d;
                s0 += pp[0]; s1 += pp[DEC]; s2 += pp[2 * DEC]; s3 += pp[3 * DEC];
            }
            if (use_gemb) {
                const __hip_bfloat16* gp = Gemb + ((size_t)(t - 1) * B + b) * NG + d;
                s0 += __bfloat162float(gp[0]);
                s1 += __bfloat162float(gp[DEC]);
                s2 += __bfloat162float(gp[2 * DEC]);
                s3 += __bfloat162float(gp[3 * DEC]);
            }
            size_t gidx = (size_t)b * DEC + d;
            float ii = 1.f / (1.f + __expf(-s0));
            float ff = 1.f / (1.f + __expf(-s1));
            float gg = tanhf(s2);
            float oo = 1.f / (1.f + __expf(-s3));
            float cn = ff * c[gidx] + ii * gg;
            float hn = oo * tanhf(cn);
            c[gidx] = cn; h[gidx] = hn; hs[bl][d] = hn;
            if (use_hall) Hall[((size_t)(t - 1) * B + b) * DEC + d] = hn;
        }
    } else {
#pragma unroll
        for (int i = 0; i < 2; ++i) {
            int idx = i * 1024 + tid;
            int bl = idx >> 9, d = idx & 511;
            hs[bl][d] = h[(size_t)(bb0 + bl) * DEC + d];
        }
    }
    if (t == S) return;
    __syncthreads();

    // wah partial: thread (a, q) covers d in [q*128, q*128+128) for all 4 b's
    {
        int a = tid & 255, q = tid >> 8;
        float a0 = 0.f, a1 = 0.f, a2 = 0.f, a3 = 0.f;
        const float* wp = Wa_w + (size_t)(q * 128) * ATT + a;
#pragma unroll 4
        for (int dd = 0; dd < 128; ++dd) {
            float w = wp[(size_t)dd * ATT];
            int d = q * 128 + dd;
            a0 = fmaf(hs[0][d], w, a0);
            a1 = fmaf(hs[1][d], w, a1);
            a2 = fmaf(hs[2][d], w, a2);
            a3 = fmaf(hs[3][d], w, a3);
        }
        wahp[q][0][a] = a0; wahp[q][1][a] = a1;
        wahp[q][2][a] = a2; wahp[q][3][a] = a3;
    }
    __syncthreads();
    {
        int bl = tid >> 8, a = tid & 255;
        wahbuf[(size_t)(bb0 + bl) * ATT + a] = Wa_b[a]
            + wahp[0][bl][a] + wahp[1][bl][a] + wahp[2][bl][a] + wahp[3][bl][a];
    }
}

// ---------------- half-attention: 256 blocks (b, half) x 512 threads ----------------
__global__ __launch_bounds__(512) void k_attn(
        const float* __restrict__ wahbuf, const float* __restrict__ Uf,
        const float* __restrict__ feat,
        const float* __restrict__ va_w, const float* __restrict__ va_b,
        float* __restrict__ ctxp, float* __restrict__ mlp) {
    int g = blockIdx.x;
    int b = g >> 1, half = g & 1;
    int tid = threadIdx.x;
    __shared__ float wahs[ATT];
    __shared__ float sc[PH];
    __shared__ float red[4];

    if (tid < ATT) wahs[tid] = wahbuf[(size_t)b * ATT + tid];
    __syncthreads();

    {   // scores: 8 waves, each takes every-8th p; lane covers 4 a's
        int w = tid >> 6, lane = tid & 63;
        float4 wv = *(const float4*)&wahs[lane * 4];
        float4 vv = *(const float4*)&va_w[lane * 4];
        float vb = va_b[0];
        for (int pl = w; pl < PH; pl += 8) {
            const float* ufp = Uf + ((size_t)b * P + half * PH + pl) * ATT + lane * 4;
            float4 u = *(const float4*)ufp;
            float ssc = vv.x * tanhf(u.x + wv.x) + vv.y * tanhf(u.y + wv.y)
                      + vv.z * tanhf(u.z + wv.z) + vv.w * tanhf(u.w + wv.w);
#pragma unroll
            for (int off = 32; off; off >>= 1) ssc += __shfl_down(ssc, off);
            if (lane == 0) sc[pl] = ssc + vb;
        }
    }
    __syncthreads();

    {   // local softmax over PH
        int lane = tid & 63;
        float v = (tid < PH) ? sc[tid] : -1e30f;
        if (tid < 128) {
            float m = v;
#pragma unroll
            for (int off = 32; off; off >>= 1) m = fmaxf(m, __shfl_down(m, off));
            if (lane == 0) red[tid >> 6] = m;
        }
        __syncthreads();
        float mh = fmaxf(red[0], red[1]);
        float e = (tid < PH) ? __expf(v - mh) : 0.f;
        if (tid < 128) {
            float l = e;
#pragma unroll
            for (int off = 32; off; off >>= 1) l += __shfl_down(l, off);
            if (lane == 0) red[2 + (tid >> 6)] = l;
        }
        __syncthreads();
        if (tid < PH) sc[tid] = e;
        if (tid == 0) {
            mlp[((size_t)half * B + b) * 2 + 0] = mh;
            mlp[((size_t)half * B + b) * 2 + 1] = red[2] + red[3];
        }
    }
    __syncthreads();

    {   // partial (unnormalized) context
        float acc = 0.f;
        const float* fb = feat + ((size_t)b * P + half * PH) * ENC + tid;
        for (int p = 0; p < PH; ++p)
            acc = fmaf(sc[p], fb[(size_t)p * ENC], acc);
        ctxp[((size_t)half * B + b) * ENC + tid] = acc;
    }
}

// ---------------- gates partial GEMM with inline ctx combine ----------------
__global__ __launch_bounds__(256) void k_gates(const float* __restrict__ emb,
        const int* __restrict__ captions, int t,
        const float* __restrict__ ctxp, const float* __restrict__ mlp,
        const float* __restrict__ h,
        const float* __restrict__ W_ih, const float* __restrict__ W_hh,
        float* __restrict__ partials, int use_gemb) {
    __shared__ float As[16][128];
    __shared__ float Bs[16][64];
    __shared__ float sw0[B], sw1[B];
    __shared__ int scap[B];
    int n0 = blockIdx.x * 64;
    int ks = blockIdx.y;
    int tid = threadIdx.x;
    int kch = use_gemb ? 128 : 160;
    if (tid < B) {
        float m0 = mlp[(size_t)tid * 2 + 0];
        float l0 = mlp[(size_t)tid * 2 + 1];
        float m1 = mlp[((size_t)B + tid) * 2 + 0];
        float l1 = mlp[((size_t)B + tid) * 2 + 1];
        float M = fmaxf(m0, m1);
        float e0 = __expf(m0 - M), e1 = __expf(m1 - M);
        float inv = 1.f / (l0 * e0 + l1 * e1);
        sw0[tid] = e0 * inv; sw1[tid] = e1 * inv;
        if (!use_gemb) scap[tid] = captions[(size_t)tid * S1 + t];
    }
    __syncthreads();
    int tx = tid & 15, ty = tid >> 4;
    float acc[8][4];
#pragma unroll
    for (int i = 0; i < 8; ++i)
#pragma unroll
        for (int j = 0; j < 4; ++j) acc[i][j] = 0.f;
    int arow = tid >> 1, ak = (tid & 1) * 8;
    int bkk = tid >> 4, bn = (tid & 15) * 4;
    for (int k0 = ks * kch; k0 < ks * kch + kch; k0 += 16) {
        {   // A tile: 8 elems per thread
            int k = k0 + ak;
            if (!use_gemb && k < EMB) {
                const float* ap = emb + (size_t)scap[arow] * EMB + k;
                float4 v0 = *(const float4*)ap;
                float4 v1 = *(const float4*)(ap + 4);
                As[ak + 0][arow] = v0.x; As[ak + 1][arow] = v0.y;
                As[ak + 2][arow] = v0.z; As[ak + 3][arow] = v0.w;
                As[ak + 4][arow] = v1.x; As[ak + 5][arow] = v1.y;
                As[ak + 6][arow] = v1.z; As[ak + 7][arow] = v1.w;
            } else {
                int kc = use_gemb ? k : (k - EMB);
                if (kc < ENC) {
                    const float* p0 = ctxp + (size_t)arow * ENC + kc;
                    const float* p1 = ctxp + ((size_t)B + arow) * ENC + kc;
                    float w0 = sw0[arow], w1 = sw1[arow];
                    float4 a0 = *(const float4*)p0;
                    float4 a1 = *(const float4*)(p0 + 4);
                    float4 b0 = *(const float4*)p1;
                    float4 b1 = *(const float4*)(p1 + 4);
                    As[ak + 0][arow] = a0.x * w0 + b0.x * w1;
                    As[ak + 1][arow] = a0.y * w0 + b0.y * w1;
                    As[ak + 2][arow] = a0.z * w0 + b0.z * w1;
                    As[ak + 3][arow] = a0.w * w0 + b0.w * w1;
                    As[ak + 4][arow] = a1.x * w0 + b1.x * w1;
                    As[ak + 5][arow] = a1.y * w0 + b1.y * w1;
                    As[ak + 6][arow] = a1.z * w0 + b1.z * w1;
                    As[ak + 7][arow] = a1.w * w0 + b1.w * w1;
                } else {
                    const float* ap = h + (size_t)arow * DEC + (kc - ENC);
                    float4 v0 = *(const float4*)ap;
                    float4 v1 = *(const float4*)(ap + 4);
                    As[ak + 0][arow] = v0.x; As[ak + 1][arow] = v0.y;
                    As[ak + 2][arow] = v0.z; As[ak + 3][arow] = v0.w;
                    As[ak + 4][arow] = v1.x; As[ak + 5][arow] = v1.y;
                    As[ak + 6][arow] = v1.z; As[ak + 7][arow] = v1.w;
                }
            }
        }
        {   // B tile
            int k = k0 + bkk;
            const float* bp;
            if (use_gemb)
                bp = (k < ENC) ? W_ih + (size_t)(k + EMB) * NG + n0 + bn
                               : W_hh + (size_t)(k - ENC) * NG + n0 + bn;
            else
                bp = (k < EMB + ENC) ? W_ih + (size_t)k * NG + n0 + bn
                                     : W_hh + (size_t)(k - EMB - ENC) * NG + n0 + bn;
            *(float4*)&Bs[bkk][bn] = *(const float4*)bp;
        }
        __syncthreads();
#pragma unroll
        for (int kk = 0; kk < 16; ++kk) {
            float4 a0 = *(const float4*)&As[kk][ty * 8];
            float4 a1 = *(const float4*)&As[kk][ty * 8 + 4];
            float4 b0 = *(const float4*)&Bs[kk][tx * 4];
            float av[8] = {a0.x, a0.y, a0.z, a0.w, a1.x, a1.y, a1.z, a1.w};
            float bv[4] = {b0.x, b0.y, b0.z, b0.w};
#pragma unroll
            for (int i = 0; i < 8; ++i)
#pragma unroll
                for (int j = 0; j < 4; ++j)
                    acc[i][j] = fmaf(av[i], bv[j], acc[i][j]);
        }
        __syncthreads();
    }
#pragma unroll
    for (int i = 0; i < 8; ++i) {
        int mrow = ty * 8 + i;
        float* pp = partials + ((size_t)ks * B + mrow) * NG + n0 + tx * 4;
        *(float4*)pp = make_float4(acc[i][0], acc[i][1], acc[i][2], acc[i][3]);
    }
}

// ---------------- output projection GEMM ----------------
__global__ __launch_bounds__(256) void k_fcn(const float* __restrict__ A,
        const float* __restrict__ Bw, const float* __restrict__ bias,
        float* __restrict__ out, int t_fix) {
    __shared__ float As[16][128];
    __shared__ float Bs[16][128];
    int m0 = blockIdx.x * 128;
    int n0 = blockIdx.y * 128;
    int tid = threadIdx.x;
    int tx = tid & 15, ty = tid >> 4;
    float acc[8][8];
#pragma unroll
    for (int i = 0; i < 8; ++i)
#pragma unroll
        for (int j = 0; j < 8; ++j) acc[i][j] = 0.f;
    int arow = tid >> 1, ak = (tid & 1) * 8;
    int bkk = tid >> 4, bn = (tid & 15) * 8;
    const float4 z4 = make_float4(0.f, 0.f, 0.f, 0.f);
    for (int k0 = 0; k0 < DEC; k0 += 16) {
        {
            const float* ap = A + (size_t)(m0 + arow) * DEC + k0 + ak;
            float4 v0 = *(const float4*)ap;
            float4 v1 = *(const float4*)(ap + 4);
            As[ak + 0][arow] = v0.x; As[ak + 1][arow] = v0.y;
            As[ak + 2][arow] = v0.z; As[ak + 3][arow] = v0.w;
            As[ak + 4][arow] = v1.x; As[ak + 5][arow] = v1.y;
            As[ak + 6][arow] = v1.z; As[ak + 7][arow] = v1.w;
        }
        {
            int n4 = n0 + bn;
            const float* bp = Bw + (size_t)(k0 + bkk) * V + n4;
            float4 v0 = (n4 < V) ? *(const float4*)bp : z4;
            float4 v1 = (n4 + 4 < V) ? *(const float4*)(bp + 4) : z4;
            *(float4*)&Bs[bkk][bn] = v0;
            *(float4*)&Bs[bkk][bn + 4] = v1;
        }
        __syncthreads();
#pragma unroll
        for (int kk = 0; kk < 16; ++kk) {
            float4 a0 = *(const float4*)&As[kk][ty * 8];
            float4 a1 = *(const float4*)&As[kk][ty * 8 + 4];
            float4 b0 = *(const float4*)&Bs[kk][tx * 8];
            float4 b1 = *(const float4*)&Bs[kk][tx * 8 + 4];
            float av[8] = {a0.x, a0.y, a0.z, a0.w, a1.x, a1.y, a1.z, a1.w};
            float bv[8] = {b0.x, b0.y, b0.z, b0.w, b1.x, b1.y, b1.z, b1.w};
#pragma unroll
            for (int i = 0; i < 8; ++i)
#pragma unroll
                for (int j = 0; j < 8; ++j)
                    acc[i][j] = fmaf(av[i], bv[j], acc[i][j]);
        }
        __syncthreads();
    }
#pragma unroll
    for (int i = 0; i < 8; ++i) {
        int mrow = m0 + ty * 8 + i;
        int bb, tt;
        if (t_fix >= 0) { bb = mrow; tt = t_fix; }
        else            { tt = mrow >> 7; bb = mrow & 127; }
        float* op = out + ((size_t)bb * S + tt) * V + n0 + tx * 8;
#pragma unroll
        for (int j = 0; j < 8; ++j) {
            int n = n0 + tx * 8 + j;
            if (n < V) op[j] = acc[i][j] + bias[n];
        }
    }
}

extern "C" void kernel_launch(void* const* d_in, const int* in_sizes, int n_in,
                              void* d_out, int out_size, void* d_ws, size_t ws_size,
                              hipStream_t stream) {
    const float* features = (const float*)d_in[0];
    const int*   captions = (const int*)d_in[1];
    const float* emb      = (const float*)d_in[2];
    const float* Ua_w     = (const float*)d_in[3];
    const float* Ua_b     = (const float*)d_in[4];
    const float* Wa_w     = (const float*)d_in[5];
    const float* Wa_b     = (const float*)d_in[6];
    const float* va_w     = (const float*)d_in[7];
    const float* va_b     = (const float*)d_in[8];
    const float* ih_w     = (const float*)d_in[9];
    const float* ih_b     = (const float*)d_in[10];
    const float* ic_w     = (const float*)d_in[11];
    const float* ic_b     = (const float*)d_in[12];
    const float* W_ih     = (const float*)d_in[13];
    const float* b_ih     = (const float*)d_in[14];
    const float* W_hh     = (const float*)d_in[15];
    const float* b_hh     = (const float*)d_in[16];
    const float* fcn_w    = (const float*)d_in[17];
    const float* fcn_b    = (const float*)d_in[18];
    float* out = (float*)d_out;
    char* wsb  = (char*)d_ws;

    size_t off = 0;
    float* Uf       = (float*)(wsb + off); off += (size_t)B * P * ATT * 4;   // 25.7MB
    float* partials = (float*)(wsb + off); off += (size_t)KS * B * NG * 4;   // 8.4MB
    float* hbuf     = (float*)(wsb + off); off += (size_t)B * DEC * 4;
    float* cbuf     = (float*)(wsb + off); off += (size_t)B * DEC * 4;
    float* wahbuf   = (float*)(wsb + off); off += (size_t)B * ATT * 4;
    float* ctxp     = (float*)(wsb + off); off += (size_t)2 * B * ENC * 4;
    float* mlp      = (float*)(wsb + off); off += 4096;
    float* meanf    = (float*)(wsb + off); off += (size_t)B * ENC * 4;
    size_t need_min = off;
    float* Hall     = (float*)(wsb + off); off += (size_t)S * B * DEC * 4;   // 67MB
    size_t need_hall = off;
    __hip_bfloat16* Gemb = (__hip_bfloat16*)(wsb + off);
    off += (size_t)S * B * NG * 2;                                           // 134MB
    size_t need_gemb = off;

    (void)need_min;
    int use_hall = ws_size >= need_hall;
    int use_gemb = ws_size >= need_gemb;

    k_mean<<<256, 256, 0, stream>>>(features, meanf);
    k_init_hc<<<256, 256, 0, stream>>>(meanf, ih_w, ih_b, ic_w, ic_b, hbuf, cbuf);
    k_uf<<<3136, 256, 0, stream>>>(features, Ua_w, Ua_b, Uf);
    if (use_gemb)
        k_gemb<<<dim3(256, 16), 256, 0, stream>>>(emb, captions, W_ih, Gemb);

    for (int t = 0; t <= S; ++t) {
        k_cellwah<<<32, 1024, 0, stream>>>(partials, Gemb, b_ih, b_hh,
                hbuf, cbuf, Hall, Wa_w, Wa_b, wahbuf, t, use_gemb, use_hall);
        if (t < S) {
            k_attn<<<256, 512, 0, stream>>>(wahbuf, Uf, features, va_w, va_b, ctxp, mlp);
            k_gates<<<dim3(32, KS), 256, 0, stream>>>(emb, captions, t, ctxp, mlp,
                    hbuf, W_ih, W_hh, partials, use_gemb);
        }
        if (!use_hall && t > 0)
            k_fcn<<<dim3(1, 40), 256, 0, stream>>>(hbuf, fcn_w, fcn_b, out, t - 1);
    }
    if (use_hall)
        k_fcn<<<dim3(256, 40), 256, 0, stream>>>(Hall, fcn_w, fcn_b, out, -1);
}